// Round 3
// baseline (544.548 us; speedup 1.0000x reference)
//
#include <hip/hip_runtime.h>
#include <stdint.h>

// GraphConv (LightGCN-style), exact JAX threefry (partitionable) dropout.
// Round 3: CSR-sorted pull-based SpMM — no f32 atomics on the output, each
// output element written exactly once, message dropout fused into the SpMM
// epilogue. CSR build (hist/scan/scatter) redone every call (graph-safe,
// deterministic work). Falls back to the round-2 atomic path if ws is small.
//
// d_out layout: [N_NODES][N_HOPS+1][D] f32. Slice 0 = concat(user,item),
// slice h+1 = hop h output. Node order user-then-item == output concat order.

static constexpr int kUsers = 50000;
static constexpr int kItems = 100000;
static constexpr int kNodes = kUsers + kItems;   // 150000
static constexpr int kNnz   = 1000000;
static constexpr int kD     = 64;
static constexpr int kHops  = 3;
static constexpr int kRowF  = (kHops + 1) * kD;  // 256 floats per node row

// scan geometry: 1024 threads x 147 elems = 150528 >= kNodes+1
static constexpr int kScanT = 1024;
static constexpr int kScanC = 147;
static constexpr int kCntN  = kScanT * kScanC;   // 150528

// ---- JAX threefry2x32 (20 rounds), bit-exact -------------------------------
__host__ __device__ inline void tf2x32(uint32_t k0, uint32_t k1,
                                       uint32_t x0, uint32_t x1,
                                       uint32_t &o0, uint32_t &o1) {
  uint32_t ks2 = k0 ^ k1 ^ 0x1BD11BDAu;
  x0 += k0; x1 += k1;
#define TF_R(r) { x0 += x1; x1 = (x1 << (r)) | (x1 >> (32 - (r))); x1 ^= x0; }
  TF_R(13) TF_R(15) TF_R(26) TF_R(6)   x0 += k1;  x1 += ks2 + 1u;
  TF_R(17) TF_R(29) TF_R(16) TF_R(24)  x0 += ks2; x1 += k0 + 2u;
  TF_R(13) TF_R(15) TF_R(26) TF_R(6)   x0 += k0;  x1 += k1 + 3u;
  TF_R(17) TF_R(29) TF_R(16) TF_R(24)  x0 += k1;  x1 += ks2 + 4u;
  TF_R(13) TF_R(15) TF_R(26) TF_R(6)   x0 += ks2; x1 += k0 + 5u;
#undef TF_R
  o0 = x0; o1 = x1;
}

// partitionable random_bits(32): XOR-fold, counter (hi,lo) = (0, i)
__device__ inline uint32_t jax_bits32(uint32_t k0, uint32_t k1, uint32_t i) {
  uint32_t b1, b2;
  tf2x32(k0, k1, 0u, i, b1, b2);
  return b1 ^ b2;
}

__device__ inline float bits_to_unit(uint32_t b) {
  return __uint_as_float((b >> 9) | 0x3f800000u) - 1.0f;
}

// ---- fast path kernels ------------------------------------------------------

// slice 0 only (slices 1..3 are fully overwritten by csr_spmm)
__global__ __launch_bounds__(256) void init_slice0(
    const float4* __restrict__ user, const float4* __restrict__ item,
    float4* __restrict__ out) {
  int i = blockIdx.x * 256 + threadIdx.x;          // over kNodes*16 float4s
  if (i >= kNodes * 16) return;
  int node = i >> 4, q = i & 15;
  float4 v = (node < kUsers) ? user[node * 16 + q]
                             : item[(node - kUsers) * 16 + q];
  out[(size_t)node * (kRowF / 4) + q] = v;
}

__global__ __launch_bounds__(256) void hist_kernel(
    const int* __restrict__ rows, int* __restrict__ cnt) {
  int e = blockIdx.x * 256 + threadIdx.x;
  if (e >= kNnz) return;
  atomicAdd(&cnt[rows[e]], 1);
}

// single-block in-place exclusive scan of cnt[0..kCntN) -> row_start; also
// copies into offs_work (scatter cursors).
__global__ __launch_bounds__(kScanT) void scan_kernel(
    int* __restrict__ cnt, int* __restrict__ offs_work) {
  int t = threadIdx.x;
  int base = t * kScanC;
  int sum = 0;
  for (int i = 0; i < kScanC; ++i) sum += cnt[base + i];
  __shared__ int ps[kScanT];
  ps[t] = sum;
  __syncthreads();
  for (int off = 1; off < kScanT; off <<= 1) {
    int v = (t >= off) ? ps[t - off] : 0;
    __syncthreads();
    ps[t] += v;
    __syncthreads();
  }
  int run = (t == 0) ? 0 : ps[t - 1];
  for (int i = 0; i < kScanC; ++i) {
    int idx = base + i;
    int c = cnt[idx];
    cnt[idx] = run;
    offs_work[idx] = run;
    run += c;
  }
}

// scatter edges into row-sorted order; precompute per-hop dropout-scaled vals
__global__ __launch_bounds__(256) void scatter_kernel(
    const int* __restrict__ rows, const int* __restrict__ cols,
    const float* __restrict__ vals, int* __restrict__ offs_work,
    int* __restrict__ cols_s, float* __restrict__ v2,
    uint32_t e00, uint32_t e01, uint32_t e10, uint32_t e11,
    uint32_t e20, uint32_t e21) {
  int e = blockIdx.x * 256 + threadIdx.x;
  if (e >= kNnz) return;
  int r = rows[e];
  int pos = atomicAdd(&offs_work[r], 1);
  cols_s[pos] = cols[e];
  float v = vals[e] * 2.0f;                        // 1/(1-0.5)
  float u0 = bits_to_unit(jax_bits32(e00, e01, (uint32_t)e));
  float u1 = bits_to_unit(jax_bits32(e10, e11, (uint32_t)e));
  float u2 = bits_to_unit(jax_bits32(e20, e21, (uint32_t)e));
  v2[pos]            = (0.5f + u0 >= 1.0f) ? v : 0.0f;
  v2[kNnz + pos]     = (0.5f + u1 >= 1.0f) ? v : 0.0f;
  v2[2 * kNnz + pos] = (0.5f + u2 >= 1.0f) ? v : 0.0f;
}

// one wave per output row; lane = dim; message dropout fused on the write
__global__ __launch_bounds__(256) void csr_spmm(
    const int* __restrict__ row_start, const int* __restrict__ cols_s,
    const float* __restrict__ v2h, float* __restrict__ out, int hop,
    uint32_t km0, uint32_t km1) {
  int wid = blockIdx.x * 4 + (threadIdx.x >> 6);   // row id
  int lane = threadIdx.x & 63;
  if (wid >= kNodes) return;
  int s = row_start[wid], t = row_start[wid + 1];
  float acc = 0.0f;
  const float* src = out + (size_t)hop * kD;
  for (int i = s; i < t; ++i) {
    float v = v2h[i];                              // wave-uniform broadcast
    if (v != 0.0f) {
      int c = cols_s[i];
      acc += v * src[(size_t)c * kRowF + lane];
    }
  }
  float u = bits_to_unit(jax_bits32(km0, km1, (uint32_t)(wid * kD + lane)));
  out[(size_t)wid * kRowF + (hop + 1) * kD + lane] =
      (u < 0.9f) ? acc / 0.9f : 0.0f;
}

// ---- fallback (round-2, proven) kernels -------------------------------------
__global__ __launch_bounds__(256) void init_full(
    const float4* __restrict__ user, const float4* __restrict__ item,
    float4* __restrict__ out) {
  int i = blockIdx.x * 256 + threadIdx.x;
  if (i >= kNodes * 16) return;
  int node = i >> 4, q = i & 15;
  float4 v = (node < kUsers) ? user[node * 16 + q]
                             : item[(node - kUsers) * 16 + q];
  float4 z = make_float4(0.f, 0.f, 0.f, 0.f);
  float4* row = out + (size_t)node * (kRowF / 4);
  row[q] = v; row[16 + q] = z; row[32 + q] = z; row[48 + q] = z;
}

__global__ __launch_bounds__(256) void spmm_atomic(
    const int* __restrict__ rows, const int* __restrict__ cols,
    const float* __restrict__ vals, float* __restrict__ out, int hop,
    uint32_t k0, uint32_t k1) {
  int e = (int)((blockIdx.x * 256u + threadIdx.x) >> 6);
  if (e >= kNnz) return;
  int lane = threadIdx.x & 63;
  float u = bits_to_unit(jax_bits32(k0, k1, (uint32_t)e));
  if (!(0.5f + u >= 1.0f)) return;
  float v = vals[e] * 2.0f;
  int r = rows[e], c = cols[e];
  float msg = v * out[(size_t)c * kRowF + hop * kD + lane];
  atomicAdd(&out[(size_t)r * kRowF + (hop + 1) * kD + lane], msg);
}

__global__ __launch_bounds__(256) void mdrop_kernel(
    float* __restrict__ out, int hop, uint32_t k0, uint32_t k1) {
  const int total = kNodes * kD;
  int j = blockIdx.x * 256 + threadIdx.x;
  if (j >= total) return;
  float u = bits_to_unit(jax_bits32(k0, k1, (uint32_t)j));
  int node = j >> 6, d = j & 63;
  size_t idx = (size_t)node * kRowF + (hop + 1) * kD + d;
  float a = out[idx];
  out[idx] = (u < 0.9f) ? a / 0.9f : 0.0f;
}

// ---- launch -----------------------------------------------------------------
extern "C" void kernel_launch(void* const* d_in, const int* in_sizes, int n_in,
                              void* d_out, int out_size, void* d_ws, size_t ws_size,
                              hipStream_t stream) {
  const float* user = (const float*)d_in[0];
  const float* item = (const float*)d_in[1];
  const int*   rows = (const int*)d_in[2];
  const int*   cols = (const int*)d_in[3];
  const float* vals = (const float*)d_in[4];
  float* out = (float*)d_out;

  // host-side key schedule (partitionable split: subkey j = tf(key, 0, j))
  uint32_t k0 = 0u, k1 = 42u;                      // jax.random.key(42)
  uint32_t ke[kHops][2], km[kHops][2];
  for (int hop = 0; hop < kHops; ++hop) {
    uint32_t n0, n1;
    tf2x32(k0, k1, 0u, 0u, n0, n1);
    tf2x32(k0, k1, 0u, 1u, ke[hop][0], ke[hop][1]);
    tf2x32(k0, k1, 0u, 2u, km[hop][0], km[hop][1]);
    k0 = n0; k1 = n1;
  }

  // ws layout
  const size_t cnt_b  = (size_t)kCntN * 4;         // row_start
  const size_t offs_b = (size_t)kCntN * 4;         // scatter cursors
  const size_t cols_b = (size_t)kNnz * 4;
  const size_t v2_b   = (size_t)kHops * kNnz * 4;
  const size_t need   = cnt_b + offs_b + cols_b + v2_b;   // ~17.2 MB

  if (ws_size >= need) {
    char* ws = (char*)d_ws;
    int*   row_start = (int*)ws;
    int*   offs_work = (int*)(ws + cnt_b);
    int*   cols_s    = (int*)(ws + cnt_b + offs_b);
    float* v2        = (float*)(ws + cnt_b + offs_b + cols_b);

    init_slice0<<<(kNodes * 16 + 255) / 256, 256, 0, stream>>>(
        (const float4*)user, (const float4*)item, (float4*)out);

    hipMemsetAsync(row_start, 0, cnt_b, stream);
    hist_kernel<<<(kNnz + 255) / 256, 256, 0, stream>>>(rows, row_start);
    scan_kernel<<<1, kScanT, 0, stream>>>(row_start, offs_work);
    scatter_kernel<<<(kNnz + 255) / 256, 256, 0, stream>>>(
        rows, cols, vals, offs_work, cols_s, v2,
        ke[0][0], ke[0][1], ke[1][0], ke[1][1], ke[2][0], ke[2][1]);

    for (int hop = 0; hop < kHops; ++hop) {
      csr_spmm<<<kNodes / 4, 256, 0, stream>>>(
          row_start, cols_s, v2 + (size_t)hop * kNnz, out, hop,
          km[hop][0], km[hop][1]);
    }
  } else {
    // fallback: proven atomic path
    init_full<<<(kNodes * 16 + 255) / 256, 256, 0, stream>>>(
        (const float4*)user, (const float4*)item, (float4*)out);
    for (int hop = 0; hop < kHops; ++hop) {
      spmm_atomic<<<(kNnz * 64 + 255) / 256, 256, 0, stream>>>(
          rows, cols, vals, out, hop, ke[hop][0], ke[hop][1]);
      mdrop_kernel<<<(kNodes * kD + 255) / 256, 256, 0, stream>>>(
          out, hop, km[hop][0], km[hop][1]);
    }
  }
}

// Round 4
// 326.682 us; speedup vs baseline: 1.6669x; 1.6669x over previous
//
#include <hip/hip_runtime.h>
#include <stdint.h>

// GraphConv (LightGCN-style), exact JAX threefry (partitionable) dropout.
// Round 4: multi-block scan (kills the 1-block scan bottleneck) + 4-edge-ILP
// pull SpMM (4 groups x 16 lanes, float4 gathers) to attack gather latency.
//
// d_out layout: [N_NODES][N_HOPS+1][D] f32. Slice 0 = concat(user,item),
// slice h+1 = hop h output. Node order user-then-item == output concat order.

static constexpr int kUsers = 50000;
static constexpr int kItems = 100000;
static constexpr int kNodes = kUsers + kItems;   // 150000
static constexpr int kNnz   = 1000000;
static constexpr int kD     = 64;
static constexpr int kHops  = 3;
static constexpr int kRowF  = (kHops + 1) * kD;  // 256 floats per node row

// scan geometry: 147 blocks x 256 threads x 4 elems = 150528 >= kNodes+1
static constexpr int kScanBlocks = 147;
static constexpr int kCntN       = kScanBlocks * 1024;   // 150528

// ---- JAX threefry2x32 (20 rounds), bit-exact -------------------------------
__host__ __device__ inline void tf2x32(uint32_t k0, uint32_t k1,
                                       uint32_t x0, uint32_t x1,
                                       uint32_t &o0, uint32_t &o1) {
  uint32_t ks2 = k0 ^ k1 ^ 0x1BD11BDAu;
  x0 += k0; x1 += k1;
#define TF_R(r) { x0 += x1; x1 = (x1 << (r)) | (x1 >> (32 - (r))); x1 ^= x0; }
  TF_R(13) TF_R(15) TF_R(26) TF_R(6)   x0 += k1;  x1 += ks2 + 1u;
  TF_R(17) TF_R(29) TF_R(16) TF_R(24)  x0 += ks2; x1 += k0 + 2u;
  TF_R(13) TF_R(15) TF_R(26) TF_R(6)   x0 += k0;  x1 += k1 + 3u;
  TF_R(17) TF_R(29) TF_R(16) TF_R(24)  x0 += k1;  x1 += ks2 + 4u;
  TF_R(13) TF_R(15) TF_R(26) TF_R(6)   x0 += ks2; x1 += k0 + 5u;
#undef TF_R
  o0 = x0; o1 = x1;
}

// partitionable random_bits(32): XOR-fold, counter (hi,lo) = (0, i)
__device__ inline uint32_t jax_bits32(uint32_t k0, uint32_t k1, uint32_t i) {
  uint32_t b1, b2;
  tf2x32(k0, k1, 0u, i, b1, b2);
  return b1 ^ b2;
}

__device__ inline float bits_to_unit(uint32_t b) {
  return __uint_as_float((b >> 9) | 0x3f800000u) - 1.0f;
}

// ---- fast path kernels ------------------------------------------------------

// slice 0 only (slices 1..3 are fully overwritten by csr_spmm)
__global__ __launch_bounds__(256) void init_slice0(
    const float4* __restrict__ user, const float4* __restrict__ item,
    float4* __restrict__ out) {
  int i = blockIdx.x * 256 + threadIdx.x;          // over kNodes*16 float4s
  if (i >= kNodes * 16) return;
  int node = i >> 4, q = i & 15;
  float4 v = (node < kUsers) ? user[node * 16 + q]
                             : item[(node - kUsers) * 16 + q];
  out[(size_t)node * (kRowF / 4) + q] = v;
}

__global__ __launch_bounds__(256) void hist_kernel(
    const int* __restrict__ rows, int* __restrict__ cnt) {
  int e = blockIdx.x * 256 + threadIdx.x;
  if (e >= kNnz) return;
  atomicAdd(&cnt[rows[e]], 1);
}

// scan phase A: per-block totals (1024 elems/block, int4 loads)
__global__ __launch_bounds__(256) void scanA(
    const int* __restrict__ cnt, int* __restrict__ partials) {
  int t = threadIdx.x;
  int4 v = ((const int4*)(cnt + blockIdx.x * 1024))[t];
  int s = v.x + v.y + v.z + v.w;
  __shared__ int sh[256];
  sh[t] = s; __syncthreads();
  for (int off = 128; off > 0; off >>= 1) {
    if (t < off) sh[t] += sh[t + off];
    __syncthreads();
  }
  if (t == 0) partials[blockIdx.x] = sh[0];
}

// scan phase B: exclusive scan of 147 partials (single tiny block)
__global__ __launch_bounds__(256) void scanB(int* __restrict__ partials) {
  int t = threadIdx.x;
  int v = (t < kScanBlocks) ? partials[t] : 0;
  __shared__ int sh[256];
  sh[t] = v; __syncthreads();
  for (int off = 1; off < 256; off <<= 1) {
    int a = (t >= off) ? sh[t - off] : 0;
    __syncthreads();
    sh[t] += a;
    __syncthreads();
  }
  if (t < kScanBlocks) partials[t] = sh[t] - v;    // exclusive
}

// scan phase C: block-local exclusive scan + base -> X (scatter cursors)
__global__ __launch_bounds__(256) void scanC(
    const int* __restrict__ cnt, const int* __restrict__ partials,
    int* __restrict__ X) {
  int t = threadIdx.x;
  int4 v = ((const int4*)(cnt + blockIdx.x * 1024))[t];
  int s = v.x + v.y + v.z + v.w;
  __shared__ int sh[256];
  sh[t] = s; __syncthreads();
  for (int off = 1; off < 256; off <<= 1) {
    int a = (t >= off) ? sh[t - off] : 0;
    __syncthreads();
    sh[t] += a;
    __syncthreads();
  }
  int base = partials[blockIdx.x] + sh[t] - s;     // exclusive for elem 4t
  int4 o;
  o.x = base; o.y = base + v.x; o.z = o.y + v.y; o.w = o.z + v.z;
  ((int4*)(X + blockIdx.x * 1024))[t] = o;
}

// scatter edges into row-sorted order; precompute per-hop dropout-scaled vals.
// After this kernel, X[r] == row_end(r) == row_start(r+1).
__global__ __launch_bounds__(256) void scatter_kernel(
    const int* __restrict__ rows, const int* __restrict__ cols,
    const float* __restrict__ vals, int* __restrict__ X,
    int* __restrict__ cols_s, float* __restrict__ v2,
    uint32_t e00, uint32_t e01, uint32_t e10, uint32_t e11,
    uint32_t e20, uint32_t e21) {
  int e = blockIdx.x * 256 + threadIdx.x;
  if (e >= kNnz) return;
  int r = rows[e];
  int pos = atomicAdd(&X[r], 1);
  cols_s[pos] = cols[e];
  float v = vals[e] * 2.0f;                        // 1/(1-0.5)
  float u0 = bits_to_unit(jax_bits32(e00, e01, (uint32_t)e));
  float u1 = bits_to_unit(jax_bits32(e10, e11, (uint32_t)e));
  float u2 = bits_to_unit(jax_bits32(e20, e21, (uint32_t)e));
  v2[pos]            = (0.5f + u0 >= 1.0f) ? v : 0.0f;
  v2[kNnz + pos]     = (0.5f + u1 >= 1.0f) ? v : 0.0f;
  v2[2 * kNnz + pos] = (0.5f + u2 >= 1.0f) ? v : 0.0f;
}

// pull SpMM: one wave per row, 4 edge-groups x 16 lanes, float4 gathers.
// s/t from post-scatter cursors X: s = X[wid-1] (0 for wid==0), t = X[wid].
__global__ __launch_bounds__(256) void csr_spmm(
    const int* __restrict__ X, const int* __restrict__ cols_s,
    const float* __restrict__ v2h, float* __restrict__ out, int hop,
    uint32_t km0, uint32_t km1) {
  int wid = blockIdx.x * 4 + (threadIdx.x >> 6);   // row id
  if (wid >= kNodes) return;
  int lane = threadIdx.x & 63;
  int g = lane >> 4, q = lane & 15;
  int s = (wid == 0) ? 0 : X[wid - 1];
  int t = X[wid];
  float4 acc = make_float4(0.f, 0.f, 0.f, 0.f);
  const float* src = out + (size_t)hop * kD;
  for (int i = s + g; i < t; i += 4) {
    float v = v2h[i];                              // group-uniform broadcast
    if (v != 0.0f) {
      int c = cols_s[i];
      float4 x = *(const float4*)(src + (size_t)c * kRowF + (q << 2));
      acc.x += v * x.x; acc.y += v * x.y; acc.z += v * x.z; acc.w += v * x.w;
    }
  }
  // reduce the 4 edge-groups (lanes xor 16, xor 32)
  acc.x += __shfl_xor(acc.x, 16); acc.y += __shfl_xor(acc.y, 16);
  acc.z += __shfl_xor(acc.z, 16); acc.w += __shfl_xor(acc.w, 16);
  acc.x += __shfl_xor(acc.x, 32); acc.y += __shfl_xor(acc.y, 32);
  acc.z += __shfl_xor(acc.z, 32); acc.w += __shfl_xor(acc.w, 32);
  // message dropout: every lane computes its own element's mask, shuffle to
  // the float4 owner lanes (q-group), lanes 0..15 write the full row.
  float u = bits_to_unit(jax_bits32(km0, km1, (uint32_t)(wid * kD + lane)));
  float m = (u < 0.9f) ? (1.0f / 0.9f) : 0.0f;
  float m0 = __shfl(m, (q << 2) + 0);
  float m1 = __shfl(m, (q << 2) + 1);
  float m2 = __shfl(m, (q << 2) + 2);
  float m3 = __shfl(m, (q << 2) + 3);
  if (g == 0) {
    float4 r = make_float4(acc.x * m0, acc.y * m1, acc.z * m2, acc.w * m3);
    *(float4*)(out + (size_t)wid * kRowF + (hop + 1) * kD + (q << 2)) = r;
  }
}

// ---- fallback (round-2, proven) kernels -------------------------------------
__global__ __launch_bounds__(256) void init_full(
    const float4* __restrict__ user, const float4* __restrict__ item,
    float4* __restrict__ out) {
  int i = blockIdx.x * 256 + threadIdx.x;
  if (i >= kNodes * 16) return;
  int node = i >> 4, q = i & 15;
  float4 v = (node < kUsers) ? user[node * 16 + q]
                             : item[(node - kUsers) * 16 + q];
  float4 z = make_float4(0.f, 0.f, 0.f, 0.f);
  float4* row = out + (size_t)node * (kRowF / 4);
  row[q] = v; row[16 + q] = z; row[32 + q] = z; row[48 + q] = z;
}

__global__ __launch_bounds__(256) void spmm_atomic(
    const int* __restrict__ rows, const int* __restrict__ cols,
    const float* __restrict__ vals, float* __restrict__ out, int hop,
    uint32_t k0, uint32_t k1) {
  int e = (int)((blockIdx.x * 256u + threadIdx.x) >> 6);
  if (e >= kNnz) return;
  int lane = threadIdx.x & 63;
  float u = bits_to_unit(jax_bits32(k0, k1, (uint32_t)e));
  if (!(0.5f + u >= 1.0f)) return;
  float v = vals[e] * 2.0f;
  int r = rows[e], c = cols[e];
  float msg = v * out[(size_t)c * kRowF + hop * kD + lane];
  atomicAdd(&out[(size_t)r * kRowF + (hop + 1) * kD + lane], msg);
}

__global__ __launch_bounds__(256) void mdrop_kernel(
    float* __restrict__ out, int hop, uint32_t k0, uint32_t k1) {
  const int total = kNodes * kD;
  int j = blockIdx.x * 256 + threadIdx.x;
  if (j >= total) return;
  float u = bits_to_unit(jax_bits32(k0, k1, (uint32_t)j));
  int node = j >> 6, d = j & 63;
  size_t idx = (size_t)node * kRowF + (hop + 1) * kD + d;
  float a = out[idx];
  out[idx] = (u < 0.9f) ? a / 0.9f : 0.0f;
}

// ---- launch -----------------------------------------------------------------
extern "C" void kernel_launch(void* const* d_in, const int* in_sizes, int n_in,
                              void* d_out, int out_size, void* d_ws, size_t ws_size,
                              hipStream_t stream) {
  const float* user = (const float*)d_in[0];
  const float* item = (const float*)d_in[1];
  const int*   rows = (const int*)d_in[2];
  const int*   cols = (const int*)d_in[3];
  const float* vals = (const float*)d_in[4];
  float* out = (float*)d_out;

  // host-side key schedule (partitionable split: subkey j = tf(key, 0, j))
  uint32_t k0 = 0u, k1 = 42u;                      // jax.random.key(42)
  uint32_t ke[kHops][2], km[kHops][2];
  for (int hop = 0; hop < kHops; ++hop) {
    uint32_t n0, n1;
    tf2x32(k0, k1, 0u, 0u, n0, n1);
    tf2x32(k0, k1, 0u, 1u, ke[hop][0], ke[hop][1]);
    tf2x32(k0, k1, 0u, 2u, km[hop][0], km[hop][1]);
    k0 = n0; k1 = n1;
  }

  // ws layout: cnt | X | cols_s | v2 | partials
  const size_t cnt_b  = (size_t)kCntN * 4;         // 602112
  const size_t x_b    = (size_t)kCntN * 4;
  const size_t cols_b = (size_t)kNnz * 4;
  const size_t v2_b   = (size_t)kHops * kNnz * 4;
  const size_t par_b  = 1024;                      // 147 ints, padded
  const size_t need   = cnt_b + x_b + cols_b + v2_b + par_b;

  if (ws_size >= need) {
    char* ws = (char*)d_ws;
    int*   cnt      = (int*)ws;
    int*   X        = (int*)(ws + cnt_b);
    int*   cols_s   = (int*)(ws + cnt_b + x_b);
    float* v2       = (float*)(ws + cnt_b + x_b + cols_b);
    int*   partials = (int*)(ws + cnt_b + x_b + cols_b + v2_b);

    init_slice0<<<(kNodes * 16 + 255) / 256, 256, 0, stream>>>(
        (const float4*)user, (const float4*)item, (float4*)out);

    hipMemsetAsync(cnt, 0, cnt_b, stream);
    hist_kernel<<<(kNnz + 255) / 256, 256, 0, stream>>>(rows, cnt);
    scanA<<<kScanBlocks, 256, 0, stream>>>(cnt, partials);
    scanB<<<1, 256, 0, stream>>>(partials);
    scanC<<<kScanBlocks, 256, 0, stream>>>(cnt, partials, X);
    scatter_kernel<<<(kNnz + 255) / 256, 256, 0, stream>>>(
        rows, cols, vals, X, cols_s, v2,
        ke[0][0], ke[0][1], ke[1][0], ke[1][1], ke[2][0], ke[2][1]);

    for (int hop = 0; hop < kHops; ++hop) {
      csr_spmm<<<kNodes / 4, 256, 0, stream>>>(
          X, cols_s, v2 + (size_t)hop * kNnz, out, hop,
          km[hop][0], km[hop][1]);
    }
  } else {
    // fallback: proven atomic path
    init_full<<<(kNodes * 16 + 255) / 256, 256, 0, stream>>>(
        (const float4*)user, (const float4*)item, (float4*)out);
    for (int hop = 0; hop < kHops; ++hop) {
      spmm_atomic<<<(kNnz * 64 + 255) / 256, 256, 0, stream>>>(
          rows, cols, vals, out, hop, ke[hop][0], ke[hop][1]);
      mdrop_kernel<<<(kNodes * kD + 255) / 256, 256, 0, stream>>>(
          out, hop, km[hop][0], km[hop][1]);
    }
  }
}

// Round 5
// 301.901 us; speedup vs baseline: 1.8037x; 1.0821x over previous
//
#include <hip/hip_runtime.h>
#include <stdint.h>

// GraphConv (LightGCN-style), exact JAX threefry (partitionable) dropout.
// Round 5: scatter writes ONE packed 8B record per edge (col[18b] + 3 keep
// bits + prescaled val) instead of 4 scattered 4B stores -> ~4x less write
// amplification. csr_spmm: 8 edge-groups x 8 lanes (2x float4 per lane) for
// 2x gather MLP; single uint2 metadata load per edge.
//
// d_out layout: [N_NODES][N_HOPS+1][D] f32. Slice 0 = concat(user,item),
// slice h+1 = hop h output. Node order user-then-item == output concat order.

static constexpr int kUsers = 50000;
static constexpr int kItems = 100000;
static constexpr int kNodes = kUsers + kItems;   // 150000
static constexpr int kNnz   = 1000000;
static constexpr int kD     = 64;
static constexpr int kHops  = 3;
static constexpr int kRowF  = (kHops + 1) * kD;  // 256 floats per node row

// scan geometry: 147 blocks x 256 threads x 4 elems = 150528 >= kNodes+1
static constexpr int kScanBlocks = 147;
static constexpr int kCntN       = kScanBlocks * 1024;   // 150528

// ---- JAX threefry2x32 (20 rounds), bit-exact -------------------------------
__host__ __device__ inline void tf2x32(uint32_t k0, uint32_t k1,
                                       uint32_t x0, uint32_t x1,
                                       uint32_t &o0, uint32_t &o1) {
  uint32_t ks2 = k0 ^ k1 ^ 0x1BD11BDAu;
  x0 += k0; x1 += k1;
#define TF_R(r) { x0 += x1; x1 = (x1 << (r)) | (x1 >> (32 - (r))); x1 ^= x0; }
  TF_R(13) TF_R(15) TF_R(26) TF_R(6)   x0 += k1;  x1 += ks2 + 1u;
  TF_R(17) TF_R(29) TF_R(16) TF_R(24)  x0 += ks2; x1 += k0 + 2u;
  TF_R(13) TF_R(15) TF_R(26) TF_R(6)   x0 += k0;  x1 += k1 + 3u;
  TF_R(17) TF_R(29) TF_R(16) TF_R(24)  x0 += k1;  x1 += ks2 + 4u;
  TF_R(13) TF_R(15) TF_R(26) TF_R(6)   x0 += ks2; x1 += k0 + 5u;
#undef TF_R
  o0 = x0; o1 = x1;
}

// partitionable random_bits(32): XOR-fold, counter (hi,lo) = (0, i)
__device__ inline uint32_t jax_bits32(uint32_t k0, uint32_t k1, uint32_t i) {
  uint32_t b1, b2;
  tf2x32(k0, k1, 0u, i, b1, b2);
  return b1 ^ b2;
}

__device__ inline float bits_to_unit(uint32_t b) {
  return __uint_as_float((b >> 9) | 0x3f800000u) - 1.0f;
}

// ---- fast path kernels ------------------------------------------------------

// slice 0 only (slices 1..3 are fully overwritten by csr_spmm)
__global__ __launch_bounds__(256) void init_slice0(
    const float4* __restrict__ user, const float4* __restrict__ item,
    float4* __restrict__ out) {
  int i = blockIdx.x * 256 + threadIdx.x;          // over kNodes*16 float4s
  if (i >= kNodes * 16) return;
  int node = i >> 4, q = i & 15;
  float4 v = (node < kUsers) ? user[node * 16 + q]
                             : item[(node - kUsers) * 16 + q];
  out[(size_t)node * (kRowF / 4) + q] = v;
}

__global__ __launch_bounds__(256) void hist_kernel(
    const int* __restrict__ rows, int* __restrict__ cnt) {
  int e = blockIdx.x * 256 + threadIdx.x;
  if (e >= kNnz) return;
  atomicAdd(&cnt[rows[e]], 1);
}

// scan phase A: per-block totals (1024 elems/block, int4 loads)
__global__ __launch_bounds__(256) void scanA(
    const int* __restrict__ cnt, int* __restrict__ partials) {
  int t = threadIdx.x;
  int4 v = ((const int4*)(cnt + blockIdx.x * 1024))[t];
  int s = v.x + v.y + v.z + v.w;
  __shared__ int sh[256];
  sh[t] = s; __syncthreads();
  for (int off = 128; off > 0; off >>= 1) {
    if (t < off) sh[t] += sh[t + off];
    __syncthreads();
  }
  if (t == 0) partials[blockIdx.x] = sh[0];
}

// scan phase B: exclusive scan of 147 partials (single tiny block)
__global__ __launch_bounds__(256) void scanB(int* __restrict__ partials) {
  int t = threadIdx.x;
  int v = (t < kScanBlocks) ? partials[t] : 0;
  __shared__ int sh[256];
  sh[t] = v; __syncthreads();
  for (int off = 1; off < 256; off <<= 1) {
    int a = (t >= off) ? sh[t - off] : 0;
    __syncthreads();
    sh[t] += a;
    __syncthreads();
  }
  if (t < kScanBlocks) partials[t] = sh[t] - v;    // exclusive
}

// scan phase C: block-local exclusive scan + base -> X (scatter cursors)
__global__ __launch_bounds__(256) void scanC(
    const int* __restrict__ cnt, const int* __restrict__ partials,
    int* __restrict__ X) {
  int t = threadIdx.x;
  int4 v = ((const int4*)(cnt + blockIdx.x * 1024))[t];
  int s = v.x + v.y + v.z + v.w;
  __shared__ int sh[256];
  sh[t] = s; __syncthreads();
  for (int off = 1; off < 256; off <<= 1) {
    int a = (t >= off) ? sh[t - off] : 0;
    __syncthreads();
    sh[t] += a;
    __syncthreads();
  }
  int base = partials[blockIdx.x] + sh[t] - s;     // exclusive for elem 4t
  int4 o;
  o.x = base; o.y = base + v.x; o.z = o.y + v.y; o.w = o.z + v.z;
  ((int4*)(X + blockIdx.x * 1024))[t] = o;
}

// scatter edges into row-sorted order; ONE 8B record per edge:
//   .x = col | keep0<<29 | keep1<<30 | keep2<<31   (col < 2^18)
//   .y = bits(2 * val)
// After this kernel, X[r] == row_end(r) == row_start(r+1).
__global__ __launch_bounds__(256) void scatter_kernel(
    const int* __restrict__ rows, const int* __restrict__ cols,
    const float* __restrict__ vals, int* __restrict__ X,
    uint2* __restrict__ ed,
    uint32_t e00, uint32_t e01, uint32_t e10, uint32_t e11,
    uint32_t e20, uint32_t e21) {
  int e = blockIdx.x * 256 + threadIdx.x;
  if (e >= kNnz) return;
  int r = rows[e];
  int pos = atomicAdd(&X[r], 1);
  float u0 = bits_to_unit(jax_bits32(e00, e01, (uint32_t)e));
  float u1 = bits_to_unit(jax_bits32(e10, e11, (uint32_t)e));
  float u2 = bits_to_unit(jax_bits32(e20, e21, (uint32_t)e));
  uint32_t packed = (uint32_t)cols[e]
                  | ((0.5f + u0 >= 1.0f) ? (1u << 29) : 0u)
                  | ((0.5f + u1 >= 1.0f) ? (1u << 30) : 0u)
                  | ((0.5f + u2 >= 1.0f) ? (1u << 31) : 0u);
  ed[pos] = make_uint2(packed, __float_as_uint(vals[e] * 2.0f));
}

// pull SpMM: one wave per row, 8 edge-groups x 8 lanes, 2x float4 per lane.
// s/t from post-scatter cursors X: s = X[wid-1] (0 for wid==0), t = X[wid].
__global__ __launch_bounds__(256) void csr_spmm(
    const int* __restrict__ X, const uint2* __restrict__ ed,
    float* __restrict__ out, int hop, uint32_t km0, uint32_t km1) {
  int wid = blockIdx.x * 4 + (threadIdx.x >> 6);   // row id
  if (wid >= kNodes) return;
  int lane = threadIdx.x & 63;
  int g = lane >> 3, q = lane & 7;                 // group, sub-lane
  int s = (wid == 0) ? 0 : X[wid - 1];
  int t = X[wid];
  float4 a0 = make_float4(0.f, 0.f, 0.f, 0.f);
  float4 a1 = make_float4(0.f, 0.f, 0.f, 0.f);
  const float* src = out + (size_t)hop * kD;
  const uint32_t kbit = 1u << (29 + hop);
  for (int i = s + g; i < t; i += 8) {
    uint2 m = ed[i];                               // group-uniform
    if (m.x & kbit) {
      float v = __uint_as_float(m.y);
      int c = (int)(m.x & 0x3FFFFu);
      const float* p = src + (size_t)c * kRowF + (q << 3);
      float4 x0 = *(const float4*)p;
      float4 x1 = *(const float4*)(p + 4);
      a0.x += v * x0.x; a0.y += v * x0.y; a0.z += v * x0.z; a0.w += v * x0.w;
      a1.x += v * x1.x; a1.y += v * x1.y; a1.z += v * x1.z; a1.w += v * x1.w;
    }
  }
  // reduce the 8 edge-groups (lane bits 3..5)
#pragma unroll
  for (int msk = 8; msk <= 32; msk <<= 1) {
    a0.x += __shfl_xor(a0.x, msk); a0.y += __shfl_xor(a0.y, msk);
    a0.z += __shfl_xor(a0.z, msk); a0.w += __shfl_xor(a0.w, msk);
    a1.x += __shfl_xor(a1.x, msk); a1.y += __shfl_xor(a1.y, msk);
    a1.z += __shfl_xor(a1.z, msk); a1.w += __shfl_xor(a1.w, msk);
  }
  // message dropout: lane l computes mask for element wid*64+l; owner lane q
  // (g==0) needs dims [q*8, q*8+8) from lanes q*8+j.
  float u = bits_to_unit(jax_bits32(km0, km1, (uint32_t)(wid * kD + lane)));
  float mk = (u < 0.9f) ? (1.0f / 0.9f) : 0.0f;
  float mv[8];
#pragma unroll
  for (int j = 0; j < 8; ++j) mv[j] = __shfl(mk, (q << 3) + j);
  if (g == 0) {
    float4 r0 = make_float4(a0.x * mv[0], a0.y * mv[1], a0.z * mv[2], a0.w * mv[3]);
    float4 r1 = make_float4(a1.x * mv[4], a1.y * mv[5], a1.z * mv[6], a1.w * mv[7]);
    float* dst = out + (size_t)wid * kRowF + (hop + 1) * kD + (q << 3);
    *(float4*)dst = r0;
    *(float4*)(dst + 4) = r1;
  }
}

// ---- fallback (round-2, proven) kernels -------------------------------------
__global__ __launch_bounds__(256) void init_full(
    const float4* __restrict__ user, const float4* __restrict__ item,
    float4* __restrict__ out) {
  int i = blockIdx.x * 256 + threadIdx.x;
  if (i >= kNodes * 16) return;
  int node = i >> 4, q = i & 15;
  float4 v = (node < kUsers) ? user[node * 16 + q]
                             : item[(node - kUsers) * 16 + q];
  float4 z = make_float4(0.f, 0.f, 0.f, 0.f);
  float4* row = out + (size_t)node * (kRowF / 4);
  row[q] = v; row[16 + q] = z; row[32 + q] = z; row[48 + q] = z;
}

__global__ __launch_bounds__(256) void spmm_atomic(
    const int* __restrict__ rows, const int* __restrict__ cols,
    const float* __restrict__ vals, float* __restrict__ out, int hop,
    uint32_t k0, uint32_t k1) {
  int e = (int)((blockIdx.x * 256u + threadIdx.x) >> 6);
  if (e >= kNnz) return;
  int lane = threadIdx.x & 63;
  float u = bits_to_unit(jax_bits32(k0, k1, (uint32_t)e));
  if (!(0.5f + u >= 1.0f)) return;
  float v = vals[e] * 2.0f;
  int r = rows[e], c = cols[e];
  float msg = v * out[(size_t)c * kRowF + hop * kD + lane];
  atomicAdd(&out[(size_t)r * kRowF + (hop + 1) * kD + lane], msg);
}

__global__ __launch_bounds__(256) void mdrop_kernel(
    float* __restrict__ out, int hop, uint32_t k0, uint32_t k1) {
  const int total = kNodes * kD;
  int j = blockIdx.x * 256 + threadIdx.x;
  if (j >= total) return;
  float u = bits_to_unit(jax_bits32(k0, k1, (uint32_t)j));
  int node = j >> 6, d = j & 63;
  size_t idx = (size_t)node * kRowF + (hop + 1) * kD + d;
  float a = out[idx];
  out[idx] = (u < 0.9f) ? a / 0.9f : 0.0f;
}

// ---- launch -----------------------------------------------------------------
extern "C" void kernel_launch(void* const* d_in, const int* in_sizes, int n_in,
                              void* d_out, int out_size, void* d_ws, size_t ws_size,
                              hipStream_t stream) {
  const float* user = (const float*)d_in[0];
  const float* item = (const float*)d_in[1];
  const int*   rows = (const int*)d_in[2];
  const int*   cols = (const int*)d_in[3];
  const float* vals = (const float*)d_in[4];
  float* out = (float*)d_out;

  // host-side key schedule (partitionable split: subkey j = tf(key, 0, j))
  uint32_t k0 = 0u, k1 = 42u;                      // jax.random.key(42)
  uint32_t ke[kHops][2], km[kHops][2];
  for (int hop = 0; hop < kHops; ++hop) {
    uint32_t n0, n1;
    tf2x32(k0, k1, 0u, 0u, n0, n1);
    tf2x32(k0, k1, 0u, 1u, ke[hop][0], ke[hop][1]);
    tf2x32(k0, k1, 0u, 2u, km[hop][0], km[hop][1]);
    k0 = n0; k1 = n1;
  }

  // ws layout: cnt | X | ed | partials
  const size_t cnt_b = (size_t)kCntN * 4;          // 602112
  const size_t x_b   = (size_t)kCntN * 4;
  const size_t ed_b  = (size_t)kNnz * 8;           // packed edge records
  const size_t par_b = 1024;                       // 147 ints, padded
  const size_t need  = cnt_b + x_b + ed_b + par_b; // ~9.2 MB

  if (ws_size >= need) {
    char* ws = (char*)d_ws;
    int*   cnt      = (int*)ws;
    int*   X        = (int*)(ws + cnt_b);
    uint2* ed       = (uint2*)(ws + cnt_b + x_b);
    int*   partials = (int*)(ws + cnt_b + x_b + ed_b);

    init_slice0<<<(kNodes * 16 + 255) / 256, 256, 0, stream>>>(
        (const float4*)user, (const float4*)item, (float4*)out);

    hipMemsetAsync(cnt, 0, cnt_b, stream);
    hist_kernel<<<(kNnz + 255) / 256, 256, 0, stream>>>(rows, cnt);
    scanA<<<kScanBlocks, 256, 0, stream>>>(cnt, partials);
    scanB<<<1, 256, 0, stream>>>(partials);
    scanC<<<kScanBlocks, 256, 0, stream>>>(cnt, partials, X);
    scatter_kernel<<<(kNnz + 255) / 256, 256, 0, stream>>>(
        rows, cols, vals, X, ed,
        ke[0][0], ke[0][1], ke[1][0], ke[1][1], ke[2][0], ke[2][1]);

    for (int hop = 0; hop < kHops; ++hop) {
      csr_spmm<<<kNodes / 4, 256, 0, stream>>>(
          X, ed, out, hop, km[hop][0], km[hop][1]);
    }
  } else {
    // fallback: proven atomic path
    init_full<<<(kNodes * 16 + 255) / 256, 256, 0, stream>>>(
        (const float4*)user, (const float4*)item, (float4*)out);
    for (int hop = 0; hop < kHops; ++hop) {
      spmm_atomic<<<(kNnz * 64 + 255) / 256, 256, 0, stream>>>(
          rows, cols, vals, out, hop, ke[hop][0], ke[hop][1]);
      mdrop_kernel<<<(kNodes * kD + 255) / 256, 256, 0, stream>>>(
          out, hop, km[hop][0], km[hop][1]);
    }
  }
}

// Round 6
// 297.475 us; speedup vs baseline: 1.8306x; 1.0149x over previous
//
#include <hip/hip_runtime.h>
#include <stdint.h>

// GraphConv (LightGCN-style), exact JAX threefry (partitionable) dropout.
// Round 6: (a) kill the 88us rocclr fill — zero cnt inside init_slice0;
// (b) csr_spmm processes 2 consecutive rows per wave (8 groups x 8 lanes per
// row, 2x float4 per lane) to double per-wave memory-level parallelism.
//
// d_out layout: [N_NODES][N_HOPS+1][D] f32. Slice 0 = concat(user,item),
// slice h+1 = hop h output. Node order user-then-item == output concat order.

static constexpr int kUsers = 50000;
static constexpr int kItems = 100000;
static constexpr int kNodes = kUsers + kItems;   // 150000
static constexpr int kNnz   = 1000000;
static constexpr int kD     = 64;
static constexpr int kHops  = 3;
static constexpr int kRowF  = (kHops + 1) * kD;  // 256 floats per node row

// scan geometry: 147 blocks x 256 threads x 4 elems = 150528 >= kNodes+1
static constexpr int kScanBlocks = 147;
static constexpr int kCntN       = kScanBlocks * 1024;   // 150528

// ---- JAX threefry2x32 (20 rounds), bit-exact -------------------------------
__host__ __device__ inline void tf2x32(uint32_t k0, uint32_t k1,
                                       uint32_t x0, uint32_t x1,
                                       uint32_t &o0, uint32_t &o1) {
  uint32_t ks2 = k0 ^ k1 ^ 0x1BD11BDAu;
  x0 += k0; x1 += k1;
#define TF_R(r) { x0 += x1; x1 = (x1 << (r)) | (x1 >> (32 - (r))); x1 ^= x0; }
  TF_R(13) TF_R(15) TF_R(26) TF_R(6)   x0 += k1;  x1 += ks2 + 1u;
  TF_R(17) TF_R(29) TF_R(16) TF_R(24)  x0 += ks2; x1 += k0 + 2u;
  TF_R(13) TF_R(15) TF_R(26) TF_R(6)   x0 += k0;  x1 += k1 + 3u;
  TF_R(17) TF_R(29) TF_R(16) TF_R(24)  x0 += k1;  x1 += ks2 + 4u;
  TF_R(13) TF_R(15) TF_R(26) TF_R(6)   x0 += ks2; x1 += k0 + 5u;
#undef TF_R
  o0 = x0; o1 = x1;
}

// partitionable random_bits(32): XOR-fold, counter (hi,lo) = (0, i)
__device__ inline uint32_t jax_bits32(uint32_t k0, uint32_t k1, uint32_t i) {
  uint32_t b1, b2;
  tf2x32(k0, k1, 0u, i, b1, b2);
  return b1 ^ b2;
}

__device__ inline float bits_to_unit(uint32_t b) {
  return __uint_as_float((b >> 9) | 0x3f800000u) - 1.0f;
}

// ---- fast path kernels ------------------------------------------------------

// slice 0 init + zero the histogram counters (replaces hipMemsetAsync).
__global__ __launch_bounds__(256) void init_slice0(
    const float4* __restrict__ user, const float4* __restrict__ item,
    float4* __restrict__ out, int4* __restrict__ cnt4) {
  int i = blockIdx.x * 256 + threadIdx.x;          // over kNodes*16 float4s
  if (i < kCntN / 4) cnt4[i] = make_int4(0, 0, 0, 0);
  if (i >= kNodes * 16) return;
  int node = i >> 4, q = i & 15;
  float4 v = (node < kUsers) ? user[node * 16 + q]
                             : item[(node - kUsers) * 16 + q];
  out[(size_t)node * (kRowF / 4) + q] = v;
}

__global__ __launch_bounds__(256) void hist_kernel(
    const int* __restrict__ rows, int* __restrict__ cnt) {
  int e = blockIdx.x * 256 + threadIdx.x;
  if (e >= kNnz) return;
  atomicAdd(&cnt[rows[e]], 1);
}

// scan phase A: per-block totals (1024 elems/block, int4 loads)
__global__ __launch_bounds__(256) void scanA(
    const int* __restrict__ cnt, int* __restrict__ partials) {
  int t = threadIdx.x;
  int4 v = ((const int4*)(cnt + blockIdx.x * 1024))[t];
  int s = v.x + v.y + v.z + v.w;
  __shared__ int sh[256];
  sh[t] = s; __syncthreads();
  for (int off = 128; off > 0; off >>= 1) {
    if (t < off) sh[t] += sh[t + off];
    __syncthreads();
  }
  if (t == 0) partials[blockIdx.x] = sh[0];
}

// scan phase B: exclusive scan of 147 partials (single tiny block)
__global__ __launch_bounds__(256) void scanB(int* __restrict__ partials) {
  int t = threadIdx.x;
  int v = (t < kScanBlocks) ? partials[t] : 0;
  __shared__ int sh[256];
  sh[t] = v; __syncthreads();
  for (int off = 1; off < 256; off <<= 1) {
    int a = (t >= off) ? sh[t - off] : 0;
    __syncthreads();
    sh[t] += a;
    __syncthreads();
  }
  if (t < kScanBlocks) partials[t] = sh[t] - v;    // exclusive
}

// scan phase C: block-local exclusive scan + base -> X (scatter cursors)
__global__ __launch_bounds__(256) void scanC(
    const int* __restrict__ cnt, const int* __restrict__ partials,
    int* __restrict__ X) {
  int t = threadIdx.x;
  int4 v = ((const int4*)(cnt + blockIdx.x * 1024))[t];
  int s = v.x + v.y + v.z + v.w;
  __shared__ int sh[256];
  sh[t] = s; __syncthreads();
  for (int off = 1; off < 256; off <<= 1) {
    int a = (t >= off) ? sh[t - off] : 0;
    __syncthreads();
    sh[t] += a;
    __syncthreads();
  }
  int base = partials[blockIdx.x] + sh[t] - s;     // exclusive for elem 4t
  int4 o;
  o.x = base; o.y = base + v.x; o.z = o.y + v.y; o.w = o.z + v.z;
  ((int4*)(X + blockIdx.x * 1024))[t] = o;
}

// scatter edges into row-sorted order; ONE 8B record per edge:
//   .x = col | keep0<<29 | keep1<<30 | keep2<<31   (col < 2^18)
//   .y = bits(2 * val)
// After this kernel, X[r] == row_end(r) == row_start(r+1).
__global__ __launch_bounds__(256) void scatter_kernel(
    const int* __restrict__ rows, const int* __restrict__ cols,
    const float* __restrict__ vals, int* __restrict__ X,
    uint2* __restrict__ ed,
    uint32_t e00, uint32_t e01, uint32_t e10, uint32_t e11,
    uint32_t e20, uint32_t e21) {
  int e = blockIdx.x * 256 + threadIdx.x;
  if (e >= kNnz) return;
  int r = rows[e];
  int pos = atomicAdd(&X[r], 1);
  float u0 = bits_to_unit(jax_bits32(e00, e01, (uint32_t)e));
  float u1 = bits_to_unit(jax_bits32(e10, e11, (uint32_t)e));
  float u2 = bits_to_unit(jax_bits32(e20, e21, (uint32_t)e));
  uint32_t packed = (uint32_t)cols[e]
                  | ((0.5f + u0 >= 1.0f) ? (1u << 29) : 0u)
                  | ((0.5f + u1 >= 1.0f) ? (1u << 30) : 0u)
                  | ((0.5f + u2 >= 1.0f) ? (1u << 31) : 0u);
  ed[pos] = make_uint2(packed, __float_as_uint(vals[e] * 2.0f));
}

// pull SpMM: one wave per TWO consecutive rows (rA = 2*pair, rB = rA+1).
// Per row: 8 edge-groups x 8 lanes, 2x float4 per lane. Rows share the X
// boundary: sA = X[rA-1], tA = X[rA] = sB, tB = X[rB]. Interleaved edge loop
// keeps both rows' ed-loads + gathers in flight (2x MLP per wave).
__global__ __launch_bounds__(256) void csr_spmm(
    const int* __restrict__ X, const uint2* __restrict__ ed,
    float* __restrict__ out, int hop, uint32_t km0, uint32_t km1) {
  int pair = blockIdx.x * 4 + (threadIdx.x >> 6);
  int rA = pair * 2;
  if (rA >= kNodes) return;
  int lane = threadIdx.x & 63;
  int g = lane >> 3, q = lane & 7;                 // group, sub-lane
  int sA = (rA == 0) ? 0 : X[rA - 1];
  int tA = X[rA];
  int tB = X[rA + 1];                              // sB == tA
  float4 a0 = make_float4(0.f, 0.f, 0.f, 0.f);
  float4 a1 = make_float4(0.f, 0.f, 0.f, 0.f);
  float4 b0 = make_float4(0.f, 0.f, 0.f, 0.f);
  float4 b1 = make_float4(0.f, 0.f, 0.f, 0.f);
  const float* src = out + (size_t)hop * kD;
  const uint32_t kbit = 1u << (29 + hop);
  int iA = sA + g, iB = tA + g;
  while (iA < tA || iB < tB) {
    if (iA < tA) {
      uint2 m = ed[iA];
      if (m.x & kbit) {
        float v = __uint_as_float(m.y);
        const float* p = src + (size_t)(m.x & 0x3FFFFu) * kRowF + (q << 3);
        float4 x0 = *(const float4*)p;
        float4 x1 = *(const float4*)(p + 4);
        a0.x += v * x0.x; a0.y += v * x0.y; a0.z += v * x0.z; a0.w += v * x0.w;
        a1.x += v * x1.x; a1.y += v * x1.y; a1.z += v * x1.z; a1.w += v * x1.w;
      }
      iA += 8;
    }
    if (iB < tB) {
      uint2 m = ed[iB];
      if (m.x & kbit) {
        float v = __uint_as_float(m.y);
        const float* p = src + (size_t)(m.x & 0x3FFFFu) * kRowF + (q << 3);
        float4 x0 = *(const float4*)p;
        float4 x1 = *(const float4*)(p + 4);
        b0.x += v * x0.x; b0.y += v * x0.y; b0.z += v * x0.z; b0.w += v * x0.w;
        b1.x += v * x1.x; b1.y += v * x1.y; b1.z += v * x1.z; b1.w += v * x1.w;
      }
      iB += 8;
    }
  }
  // reduce the 8 edge-groups (lane bits 3..5) for both rows
#pragma unroll
  for (int msk = 8; msk <= 32; msk <<= 1) {
    a0.x += __shfl_xor(a0.x, msk); a0.y += __shfl_xor(a0.y, msk);
    a0.z += __shfl_xor(a0.z, msk); a0.w += __shfl_xor(a0.w, msk);
    a1.x += __shfl_xor(a1.x, msk); a1.y += __shfl_xor(a1.y, msk);
    a1.z += __shfl_xor(a1.z, msk); a1.w += __shfl_xor(a1.w, msk);
    b0.x += __shfl_xor(b0.x, msk); b0.y += __shfl_xor(b0.y, msk);
    b0.z += __shfl_xor(b0.z, msk); b0.w += __shfl_xor(b0.w, msk);
    b1.x += __shfl_xor(b1.x, msk); b1.y += __shfl_xor(b1.y, msk);
    b1.z += __shfl_xor(b1.z, msk); b1.w += __shfl_xor(b1.w, msk);
  }
  // message dropout masks: lane l holds mask for (rA, dim l) and (rB, dim l).
  float uA = bits_to_unit(jax_bits32(km0, km1, (uint32_t)(rA * kD + lane)));
  float uB = bits_to_unit(jax_bits32(km0, km1, (uint32_t)((rA + 1) * kD + lane)));
  float mA = (uA < 0.9f) ? (1.0f / 0.9f) : 0.0f;
  float mB = (uB < 0.9f) ? (1.0f / 0.9f) : 0.0f;
  // writers: group 0 -> row rA, group 1 -> row rB; each lane writes dims
  // [8q, 8q+8) as 2x float4, masks shuffled from the mask owners.
  float w[8];
#pragma unroll
  for (int j = 0; j < 8; ++j) {
    float wA = __shfl(mA, (q << 3) + j);
    float wB = __shfl(mB, (q << 3) + j);
    w[j] = (g == 0) ? wA : wB;
  }
  if (g == 0) {
    float* dst = out + (size_t)rA * kRowF + (hop + 1) * kD + (q << 3);
    *(float4*)dst       = make_float4(a0.x * w[0], a0.y * w[1], a0.z * w[2], a0.w * w[3]);
    *(float4*)(dst + 4) = make_float4(a1.x * w[4], a1.y * w[5], a1.z * w[6], a1.w * w[7]);
  } else if (g == 1) {
    float* dst = out + (size_t)(rA + 1) * kRowF + (hop + 1) * kD + (q << 3);
    *(float4*)dst       = make_float4(b0.x * w[0], b0.y * w[1], b0.z * w[2], b0.w * w[3]);
    *(float4*)(dst + 4) = make_float4(b1.x * w[4], b1.y * w[5], b1.z * w[6], b1.w * w[7]);
  }
}

// ---- fallback (round-2, proven) kernels -------------------------------------
__global__ __launch_bounds__(256) void init_full(
    const float4* __restrict__ user, const float4* __restrict__ item,
    float4* __restrict__ out) {
  int i = blockIdx.x * 256 + threadIdx.x;
  if (i >= kNodes * 16) return;
  int node = i >> 4, q = i & 15;
  float4 v = (node < kUsers) ? user[node * 16 + q]
                             : item[(node - kUsers) * 16 + q];
  float4 z = make_float4(0.f, 0.f, 0.f, 0.f);
  float4* row = out + (size_t)node * (kRowF / 4);
  row[q] = v; row[16 + q] = z; row[32 + q] = z; row[48 + q] = z;
}

__global__ __launch_bounds__(256) void spmm_atomic(
    const int* __restrict__ rows, const int* __restrict__ cols,
    const float* __restrict__ vals, float* __restrict__ out, int hop,
    uint32_t k0, uint32_t k1) {
  int e = (int)((blockIdx.x * 256u + threadIdx.x) >> 6);
  if (e >= kNnz) return;
  int lane = threadIdx.x & 63;
  float u = bits_to_unit(jax_bits32(k0, k1, (uint32_t)e));
  if (!(0.5f + u >= 1.0f)) return;
  float v = vals[e] * 2.0f;
  int r = rows[e], c = cols[e];
  float msg = v * out[(size_t)c * kRowF + hop * kD + lane];
  atomicAdd(&out[(size_t)r * kRowF + (hop + 1) * kD + lane], msg);
}

__global__ __launch_bounds__(256) void mdrop_kernel(
    float* __restrict__ out, int hop, uint32_t k0, uint32_t k1) {
  const int total = kNodes * kD;
  int j = blockIdx.x * 256 + threadIdx.x;
  if (j >= total) return;
  float u = bits_to_unit(jax_bits32(k0, k1, (uint32_t)j));
  int node = j >> 6, d = j & 63;
  size_t idx = (size_t)node * kRowF + (hop + 1) * kD + d;
  float a = out[idx];
  out[idx] = (u < 0.9f) ? a / 0.9f : 0.0f;
}

// ---- launch -----------------------------------------------------------------
extern "C" void kernel_launch(void* const* d_in, const int* in_sizes, int n_in,
                              void* d_out, int out_size, void* d_ws, size_t ws_size,
                              hipStream_t stream) {
  const float* user = (const float*)d_in[0];
  const float* item = (const float*)d_in[1];
  const int*   rows = (const int*)d_in[2];
  const int*   cols = (const int*)d_in[3];
  const float* vals = (const float*)d_in[4];
  float* out = (float*)d_out;

  // host-side key schedule (partitionable split: subkey j = tf(key, 0, j))
  uint32_t k0 = 0u, k1 = 42u;                      // jax.random.key(42)
  uint32_t ke[kHops][2], km[kHops][2];
  for (int hop = 0; hop < kHops; ++hop) {
    uint32_t n0, n1;
    tf2x32(k0, k1, 0u, 0u, n0, n1);
    tf2x32(k0, k1, 0u, 1u, ke[hop][0], ke[hop][1]);
    tf2x32(k0, k1, 0u, 2u, km[hop][0], km[hop][1]);
    k0 = n0; k1 = n1;
  }

  // ws layout: cnt | X | ed | partials
  const size_t cnt_b = (size_t)kCntN * 4;          // 602112
  const size_t x_b   = (size_t)kCntN * 4;
  const size_t ed_b  = (size_t)kNnz * 8;           // packed edge records
  const size_t par_b = 1024;                       // 147 ints, padded
  const size_t need  = cnt_b + x_b + ed_b + par_b; // ~9.2 MB

  if (ws_size >= need) {
    char* ws = (char*)d_ws;
    int*   cnt      = (int*)ws;
    int*   X        = (int*)(ws + cnt_b);
    uint2* ed       = (uint2*)(ws + cnt_b + x_b);
    int*   partials = (int*)(ws + cnt_b + x_b + ed_b);

    init_slice0<<<(kNodes * 16 + 255) / 256, 256, 0, stream>>>(
        (const float4*)user, (const float4*)item, (float4*)out, (int4*)cnt);

    hist_kernel<<<(kNnz + 255) / 256, 256, 0, stream>>>(rows, cnt);
    scanA<<<kScanBlocks, 256, 0, stream>>>(cnt, partials);
    scanB<<<1, 256, 0, stream>>>(partials);
    scanC<<<kScanBlocks, 256, 0, stream>>>(cnt, partials, X);
    scatter_kernel<<<(kNnz + 255) / 256, 256, 0, stream>>>(
        rows, cols, vals, X, ed,
        ke[0][0], ke[0][1], ke[1][0], ke[1][1], ke[2][0], ke[2][1]);

    const int nPairs = kNodes / 2;                 // 75000
    for (int hop = 0; hop < kHops; ++hop) {
      csr_spmm<<<(nPairs + 3) / 4, 256, 0, stream>>>(
          X, ed, out, hop, km[hop][0], km[hop][1]);
    }
  } else {
    // fallback: proven atomic path
    init_full<<<(kNodes * 16 + 255) / 256, 256, 0, stream>>>(
        (const float4*)user, (const float4*)item, (float4*)out);
    for (int hop = 0; hop < kHops; ++hop) {
      spmm_atomic<<<(kNnz * 64 + 255) / 256, 256, 0, stream>>>(
          rows, cols, vals, out, hop, ke[hop][0], ke[hop][1]);
      mdrop_kernel<<<(kNodes * kD + 255) / 256, 256, 0, stream>>>(
          out, hop, km[hop][0], km[hop][1]);
    }
  }
}